// Round 3
// baseline (70.446 us; speedup 1.0000x reference)
//
#include <hip/hip_runtime.h>
#include <hip/hip_cooperative_groups.h>

namespace cg = cooperative_groups;

// GlassBlur (ImageNet-C) sigma=0.05 -> gaussian radius 0 -> blur is identity.
// Op == 49284 sequential pixel swaps == one exact permutation of fp32 values.
// Fused single cooperative kernel:
//   Phase 1: blocks 0..221 each compose one swap-row's 222 swaps into a segment
//     permutation over rows {h-1,h} (4-register sliding window, wave-uniform
//     chain via readlane-broadcast 2-bit codes). Table: unsigned per column,
//     (bot<<16)|top, cell = (row<<8)|col.
//   grid.sync() (+ device fences: per-XCD L2s are not coherent).
//   Phase 2: block b gathers image row b: per pixel chase through segments
//     (expected ~2 dependent loads), exact fp32 gather + clamp.

static constexpr int IMH = 224;
static constexpr int IMW = 224;
static constexpr int NROW = 222;     // swap rows h = 2..223

__global__ __launch_bounds__(64) void glass_fused(const float* __restrict__ img,
                                                  const int2* __restrict__ dxy,
                                                  unsigned* __restrict__ table,
                                                  float* __restrict__ out) {
    int blk = blockIdx.x;            // 0..223
    int lane = threadIdx.x;          // 0..63

    if (blk < NROW) {
        int row = blk;
        int h = row + 2;             // swap-row simulated by this block's wave
        int base = (221 - row) * 222;

        // Coalesced load of the row's 222 dxy entries -> 2-bit codes per lane.
        unsigned codes[4] = {0u, 0u, 0u, 0u};
        {
            int2 d;
            d = dxy[base + lane];        codes[0] = ((d.y < 0) ? 2u : 0u) | ((d.x < 0) ? 1u : 0u);
            d = dxy[base + lane + 64];   codes[1] = ((d.y < 0) ? 2u : 0u) | ((d.x < 0) ? 1u : 0u);
            d = dxy[base + lane + 128];  codes[2] = ((d.y < 0) ? 2u : 0u) | ((d.x < 0) ? 1u : 0u);
            if (lane + 192 < 222) {
                d = dxy[base + lane + 192];
                codes[3] = ((d.y < 0) ? 2u : 0u) | ((d.x < 0) ? 1u : 0u);
            }
        }

        // Sliding 4-cell window: column w (t1=row h-1, b1=row h), column w-1 (t0,b0).
        unsigned t1 = ((unsigned)(h - 1) << 8) | 223u;
        unsigned b1 = ((unsigned)h << 8) | 223u;
        unsigned t0 = ((unsigned)(h - 1) << 8) | 222u;
        unsigned b0 = ((unsigned)h << 8) | 222u;

        unsigned v0 = 0, v1 = 0, v2 = 0, v3 = 0;  // lane (i&63) keeps entry of iter i

        #pragma unroll
        for (int i = 0; i < 222; ++i) {           // iteration i handles column w = 223-i
            unsigned code = (unsigned)__builtin_amdgcn_readlane((int)codes[i >> 6], i & 63);
            bool dy = (code & 2u) != 0u;
            bool dx = (code & 1u) != 0u;
            unsigned ob1 = b1;
            unsigned partner = dy ? (dx ? t0 : t1) : (dx ? b0 : b1);
            b1 = partner;
            t0 = (dy && dx) ? ob1 : t0;
            t1 = (dy && !dx) ? ob1 : t1;
            b0 = (!dy && dx) ? ob1 : b0;
            unsigned val = (b1 << 16) | t1;       // column w final: (bot<<16)|top
            if ((i & 63) == lane) {
                switch (i >> 6) {
                    case 0: v0 = val; break;
                    case 1: v1 = val; break;
                    case 2: v2 = val; break;
                    default: v3 = val; break;
                }
            }
            // slide window left
            t1 = t0; b1 = b0;
            unsigned wn = (unsigned)(221 - i);    // = w-2
            t0 = ((unsigned)(h - 1) << 8) | wn;
            b0 = ((unsigned)h << 8) | wn;
        }

        unsigned* rowTab = table + row * IMW;
        // iter i -> w = 223-i; chunk k stored by lane i-64k at column (223-64k)-lane
        rowTab[223 - lane] = v0;
        rowTab[159 - lane] = v1;
        rowTab[95 - lane]  = v2;
        if (lane < 30) rowTab[31 - lane] = v3;    // i = 192..221 -> w = 31..2
        if (lane == 0) {
            rowTab[1] = (b1 << 16) | t1;          // column 1 (carried window)
            rowTab[0] = (((unsigned)h << 8) << 16) | ((unsigned)(h - 1) << 8);
        }
    }

    // Cross-XCD visibility: release writeback, grid barrier, acquire invalidate.
    __threadfence();
    cg::this_grid().sync();
    __threadfence();

    // Phase 2: this block gathers image row r = blk.
    int r = blk;
    #pragma unroll
    for (int k = 0; k < 4; ++k) {
        int c = lane + 64 * k;
        if (c < IMW) {
            int qr = r, qc = c;
            if (r >= 1) {
                int h = (r < 2) ? 2 : r;          // first segment whose domain holds r
                while (h <= 223) {
                    unsigned v = table[(h - 2) * IMW + qc];
                    unsigned sel = (qr == h) ? (v >> 16) : (v & 0xffffu);
                    qr = (int)(sel >> 8);
                    qc = (int)(sel & 255u);
                    if (qr != h) break;           // landed in row h-1 -> frozen
                    ++h;
                }
            }
            int q = qr * IMW + qc;
            int p = r * IMW + c;
            float a0 = img[3 * q + 0];
            float a1 = img[3 * q + 1];
            float a2 = img[3 * q + 2];
            out[3 * p + 0] = fminf(fmaxf(a0, 0.0f), 1.0f);
            out[3 * p + 1] = fminf(fmaxf(a1, 0.0f), 1.0f);
            out[3 * p + 2] = fminf(fmaxf(a2, 0.0f), 1.0f);
        }
    }
}

extern "C" void kernel_launch(void* const* d_in, const int* in_sizes, int n_in,
                              void* d_out, int out_size, void* d_ws, size_t ws_size,
                              hipStream_t stream) {
    const float* img = (const float*)d_in[0];
    const int2* dxy = (const int2*)d_in[1];
    float* out = (float*)d_out;
    unsigned* table = (unsigned*)d_ws;            // 222*224*4 = 198,912 B

    void* args[] = {(void*)&img, (void*)&dxy, (void*)&table, (void*)&out};
    hipLaunchCooperativeKernel((const void*)glass_fused, dim3(IMH), dim3(64),
                               args, 0, stream);
}

// Round 5
// 32.223 us; speedup vs baseline: 2.1862x; 2.1862x over previous
//
#include <hip/hip_runtime.h>

// GlassBlur (ImageNet-C) sigma=0.05 -> gaussian radius 0 -> blur is identity.
// Op == 49284 sequential pixel swaps == one exact permutation of fp32 values.
//
// Single ordinary kernel, no grid sync, no workspace:
// For swap-row h, the 222 swaps compose into a segment permutation over rows
// {h-1,h}. Closed form of the window machine (carry analysis): only the bottom
// occupant B propagates, and only through runs of code==01 (dy=0,dx=-1):
//   B_in(w) = (h, w + run01_right_of(w)),
//   T_in(w) = B_in(w+1) if code(w+1)==11 else (h-1,w)
//   entry(w): c=00:(T,B)  c=01:(T,(h,w-1))  c=10:(B,T)  c=11:(T,(h-1,w-1))
//   column 1 (carry out of col 2): top = c(2)==11 ? B_in(2) : (h-1,1)
//                                  bot = c(2)==01 ? B_in(2) : (h,1)
//   column 0: identity.
// Each block = 1 wave = 1 output row; per segment h it ballot-builds the code
// masks and every lane evaluates its own entry in-register; chase continues
// while the pixel stays in row h (expected depth ~2, block max ~12).
// R4 bug fixed: lanes 32..63 of the k=3 column group (c = lane+192 >= 224)
// are inactive and their store is guarded (R4 wrote OOB into the next row).

static constexpr int IMH = 224;
static constexpr int IMW = 224;
static constexpr int NSW = 49284;    // total swap count

typedef unsigned long long u64;

__device__ __forceinline__ u64 sel4(u64 m0, u64 m1, u64 m2, u64 m3, int c) {
    u64 a = (c & 1) ? m1 : m0;
    u64 b = (c & 1) ? m3 : m2;
    return (c & 2) ? b : a;
}

__device__ __forceinline__ int getbit4(u64 m0, u64 m1, u64 m2, u64 m3, int j) {
    return (int)((sel4(m0, m1, m2, m3, j >> 6) >> (j & 63)) & 1ull);
}

// run of consecutive set bits at positions i-1, i-2, ...  (caller ensures i>=1)
__device__ __forceinline__ int run_below(u64 p0, u64 p1, u64 p2, u64 p3, int i) {
    int c = i >> 6, b = i & 63;
    u64 lo = sel4(p0, p1, p2, p3, c);
    u64 lw = (c > 0) ? sel4(p0, p1, p2, p3, c - 1) : 0ull;
    u64 val = b ? ((lo << (64 - b)) | (lw >> b)) : lw;
    u64 nv = ~val;
    int k = nv ? __builtin_clzll(nv) : 64;
    if (k >= 64) {                       // run continues past 64-bit window (rare)
        while (k < i && getbit4(p0, p1, p2, p3, i - 1 - k)) ++k;
    }
    return k;
}

// source cell ((row<<8)|col) for position (qr,qc) under segment h's permutation
__device__ __forceinline__ int seg_entry(int qr, int qc, int h,
        u64 y0, u64 y1, u64 y2, u64 y3,
        u64 x0, u64 x1, u64 x2, u64 x3,
        u64 p0, u64 p1, u64 p2, u64 p3) {
    bool top = (qr != h);                // qr == h-1
    if (qc == 0) return qr << 8;         // column 0 never touched
    if (qc == 1) {                       // carried column
        int cc = 2 * getbit4(y0, y1, y2, y3, 221) + getbit4(x0, x1, x2, x3, 221);
        int bcol = 2 + run_below(p0, p1, p2, p3, 221);
        if (top) return (cc == 3) ? ((h << 8) | bcol) : (((h - 1) << 8) | 1);
        else     return (cc == 1) ? ((h << 8) | bcol) : ((h << 8) | 1);
    }
    int i = 223 - qc;                    // iteration index of column qc
    int ci = 2 * getbit4(y0, y1, y2, y3, i) + getbit4(x0, x1, x2, x3, i);
    int Bcol = qc + ((i > 0) ? run_below(p0, p1, p2, p3, i) : 0);
    int Trow = h - 1, Tcol = qc;
    if (i > 0) {
        int cm = 2 * getbit4(y0, y1, y2, y3, i - 1) + getbit4(x0, x1, x2, x3, i - 1);
        if (cm == 3) {
            Trow = h;
            Tcol = qc + 1 + ((i > 1) ? run_below(p0, p1, p2, p3, i - 1) : 0);
        }
    }
    int T = (Trow << 8) | Tcol;
    int B = (h << 8) | Bcol;
    switch (ci) {
        case 0:  return top ? T : B;
        case 1:  return top ? T : ((h << 8) | (qc - 1));
        case 2:  return top ? B : T;
        default: return top ? T : (((h - 1) << 8) | (qc - 1));
    }
}

__global__ __launch_bounds__(64) void glass_onepass(const float* __restrict__ img,
                                                    const int2* __restrict__ dxy,
                                                    float* __restrict__ out) {
    int r = blockIdx.x;                  // output image row
    int lane = threadIdx.x;

    // 4 chase states per lane: columns lane, lane+64, lane+128, lane+192
    int s0 = (r << 8) | lane;
    int s1 = (r << 8) | (lane + 64);
    int s2 = (r << 8) | (lane + 128);
    int s3 = (r << 8) | ((lane + 192) & 255);
    bool act = (r >= 1);
    bool a0 = act, a1 = act, a2 = act;
    bool a3 = act && (lane + 192 < IMW);   // columns >= 224 don't exist

    int h = (r < 2) ? 2 : r;             // first segment whose domain {h-1,h} holds r
    int base = (223 - h) * 222;
    int2 d0 = {0,0}, d1 = {0,0}, d2 = {0,0}, d3 = {0,0};
    if (r >= 1) {
        d0 = dxy[base + lane];
        d1 = dxy[base + lane + 64];
        d2 = dxy[base + lane + 128];
        d3 = dxy[min(base + lane + 192, NSW - 1)];
    }

    while (h <= 223 && __any((int)(a0 | a1 | a2 | a3))) {
        // build wave-uniform code masks for segment h
        u64 y0 = __ballot(d0.y < 0), x0 = __ballot(d0.x < 0);
        u64 y1 = __ballot(d1.y < 0), x1 = __ballot(d1.x < 0);
        u64 y2 = __ballot(d2.y < 0), x2 = __ballot(d2.x < 0);
        u64 y3 = __ballot(d3.y < 0), x3 = __ballot(d3.x < 0);
        u64 p0 = ~y0 & x0, p1 = ~y1 & x1, p2 = ~y2 & x2;
        u64 p3 = (~y3 & x3) & ((1ull << 30) - 1);   // row has 222 codes

        // prefetch next segment (clamped; unused if h==223)
        int nb = (223 - min(h + 1, 223)) * 222;
        int2 n0 = dxy[nb + lane];
        int2 n1 = dxy[nb + lane + 64];
        int2 n2 = dxy[nb + lane + 128];
        int2 n3 = dxy[min(nb + lane + 192, NSW - 1)];

        if (a0) { s0 = seg_entry(s0 >> 8, s0 & 255, h, y0,y1,y2,y3, x0,x1,x2,x3, p0,p1,p2,p3); a0 = (s0 >> 8) == h; }
        if (a1) { s1 = seg_entry(s1 >> 8, s1 & 255, h, y0,y1,y2,y3, x0,x1,x2,x3, p0,p1,p2,p3); a1 = (s1 >> 8) == h; }
        if (a2) { s2 = seg_entry(s2 >> 8, s2 & 255, h, y0,y1,y2,y3, x0,x1,x2,x3, p0,p1,p2,p3); a2 = (s2 >> 8) == h; }
        if (a3) { s3 = seg_entry(s3 >> 8, s3 & 255, h, y0,y1,y2,y3, x0,x1,x2,x3, p0,p1,p2,p3); a3 = (s3 >> 8) == h; }

        d0 = n0; d1 = n1; d2 = n2; d3 = n3;
        ++h;
    }

    // exact fp32 gather + clamp, coalesced store
    int pbase = r * IMW;
    #pragma unroll
    for (int k = 0; k < 4; ++k) {
        int c = lane + 64 * k;
        if (c < IMW) {
            int s = (k == 0) ? s0 : (k == 1) ? s1 : (k == 2) ? s2 : s3;
            int q = (s >> 8) * IMW + (s & 255);
            int p = pbase + c;
            float v0 = img[3 * q + 0];
            float v1 = img[3 * q + 1];
            float v2 = img[3 * q + 2];
            out[3 * p + 0] = fminf(fmaxf(v0, 0.0f), 1.0f);
            out[3 * p + 1] = fminf(fmaxf(v1, 0.0f), 1.0f);
            out[3 * p + 2] = fminf(fmaxf(v2, 0.0f), 1.0f);
        }
    }
}

extern "C" void kernel_launch(void* const* d_in, const int* in_sizes, int n_in,
                              void* d_out, int out_size, void* d_ws, size_t ws_size,
                              hipStream_t stream) {
    const float* img = (const float*)d_in[0];
    const int2* dxy = (const int2*)d_in[1];
    float* out = (float*)d_out;
    hipLaunchKernelGGL(glass_onepass, dim3(IMH), dim3(64), 0, stream, img, dxy, out);
}

// Round 6
// 13.588 us; speedup vs baseline: 5.1843x; 2.3714x over previous
//
#include <hip/hip_runtime.h>

// GlassBlur (ImageNet-C) sigma=0.05 -> gaussian radius 0 -> blur is identity.
// Op == 49284 sequential pixel swaps == one exact permutation of fp32 values.
//
// Single kernel, no grid sync, no workspace. For swap-row h the 222 swaps
// compose into a segment permutation over rows {h-1,h}; closed form of the
// 4-register window machine (only the bottom occupant B propagates, through
// runs of code 01 = (dy=0,dx=-1)):
//   entry(qc): i=223-qc, ci=code(i), cm=code(i-1), run=run01 below idx
//     top   : ci==2 -> (h, qc+run(i)); cm==3 -> (h, qc+1+run(i-1)); else (h-1,qc)
//     bottom: ci==0 -> (h, qc+run(i)); ci==1 -> (h,qc-1); ci==3 -> (h-1,qc-1)
//             ci==2 -> cm==3 ? (h, qc+1+run(i-1)) : (h-1, qc)
//   qc==0/1 collapse into the same formulas when mask bits >=222 are zero
//   (verified algebraically against the exact window machine).
// Only the FIRST segment step (h=r, r>=2) is a bottom entry; all later steps
// are top entries (pixel row == h means top of segment h+1) -> cheap path.
// 224 blocks x 256 threads: thread t owns column t; each of the 4 waves
// chases independently (own ballot masks, own loop, no __syncthreads).

static constexpr int IMH = 224;
static constexpr int IMW = 224;
static constexpr int NSW = 49284;    // total swap count

typedef unsigned long long u64;

__device__ __forceinline__ u64 sel4(u64 m0, u64 m1, u64 m2, u64 m3, int c) {
    u64 a = (c & 1) ? m1 : m0;
    u64 b = (c & 1) ? m3 : m2;
    return (c & 2) ? b : a;
}

__device__ __forceinline__ int getbit4(u64 m0, u64 m1, u64 m2, u64 m3, int j) {
    return (int)((sel4(m0, m1, m2, m3, j >> 6) >> (j & 63)) & 1ull);
}

// run of consecutive set bits at positions i-1, i-2, ...  (i in [0,223])
__device__ __forceinline__ int run_below(u64 p0, u64 p1, u64 p2, u64 p3, int i) {
    int c = i >> 6, b = i & 63;
    u64 lo = sel4(p0, p1, p2, p3, c);
    u64 lw = (c > 0) ? sel4(p0, p1, p2, p3, c - 1) : 0ull;
    u64 val = b ? ((lo << (64 - b)) | (lw >> b)) : lw;
    u64 nv = ~val;
    int k = nv ? __builtin_clzll(nv) : 64;
    if (k >= 64) {                       // run crosses the 64-bit window (rare)
        while (k < i && getbit4(p0, p1, p2, p3, i - 1 - k)) ++k;
    }
    return k;
}

__global__ __launch_bounds__(256) void glass_onepass(const float* __restrict__ img,
                                                     const int2* __restrict__ dxy,
                                                     float* __restrict__ out) {
    int r = blockIdx.x;                  // output image row
    int t = threadIdx.x;                 // 0..255; owns column t (if < 224)
    int lane = t & 63;
    int c = t;

    int s = (r << 8) | c;                // chase state: (row<<8)|col
    bool a = (r >= 1) && (c < IMW);

    int h = (r < 2) ? 2 : r;             // first segment whose domain {h-1,h} holds r
    bool bottom = (r >= 2);              // first step sees the pixel in row h (bottom)
    int base = (223 - h) * 222;
    int2 d0 = {0,0}, d1 = {0,0}, d2 = {0,0}, d3 = {0,0};
    if (r >= 1) {
        d0 = dxy[base + lane];
        d1 = dxy[base + lane + 64];
        d2 = dxy[base + lane + 128];
        d3 = dxy[min(base + lane + 192, NSW - 1)];
    }

    while (h <= 223 && __any((int)a)) {
        // per-wave code masks for segment h (positions >= 222 forced to zero)
        u64 y0 = __ballot(d0.y < 0), x0 = __ballot(d0.x < 0);
        u64 y1 = __ballot(d1.y < 0), x1 = __ballot(d1.x < 0);
        u64 y2 = __ballot(d2.y < 0), x2 = __ballot(d2.x < 0);
        u64 y3 = __ballot(d3.y < 0) & 0x3fffffffull;
        u64 x3 = __ballot(d3.x < 0) & 0x3fffffffull;
        u64 p0 = ~y0 & x0, p1 = ~y1 & x1, p2 = ~y2 & x2, p3 = ~y3 & x3;

        // prefetch next segment's codes (clamped; unused if h==223)
        int nb = (223 - min(h + 1, 223)) * 222;
        int2 n0 = dxy[nb + lane];
        int2 n1 = dxy[nb + lane + 64];
        int2 n2 = dxy[nb + lane + 128];
        int2 n3 = dxy[min(nb + lane + 192, NSW - 1)];

        if (a) {
            int qc = s & 255;
            int i = 223 - qc;
            int yi = getbit4(y0, y1, y2, y3, i);
            int xi = getbit4(x0, x1, x2, x3, i);
            int cm3 = (i > 0) ? (getbit4(y0, y1, y2, y3, i - 1) &
                                 getbit4(x0, x1, x2, x3, i - 1)) : 0;
            int row, col;
            if (bottom) {                // wave-uniform: first iteration only
                int ci = 2 * yi + xi;
                int idx = (ci == 0) ? i : max(i - 1, 0);
                int run = run_below(p0, p1, p2, p3, idx);
                if (ci == 0)      { row = h;     col = qc + run; }
                else if (ci == 1) { row = h;     col = qc - 1; }
                else if (ci == 3) { row = h - 1; col = qc - 1; }
                else {               // ci == 2 -> incoming top occupant
                    if (cm3) { row = h;     col = qc + 1 + run; }
                    else     { row = h - 1; col = qc; }
                }
            } else {                     // top entry: cheap path
                int ci2 = yi & (xi ^ 1);
                int idx = ci2 ? i : max(i - 1, 0);
                int run = run_below(p0, p1, p2, p3, idx);
                if (ci2)      { row = h;     col = qc + run; }
                else if (cm3) { row = h;     col = qc + 1 + run; }
                else          { row = h - 1; col = qc; }
            }
            s = (row << 8) | col;
            a = (row == h);              // stays in domain of segment h+1 (as top)
        }
        bottom = false;
        d0 = n0; d1 = n1; d2 = n2; d3 = n3;
        ++h;
    }

    if (c < IMW) {                       // exact fp32 gather + clamp
        int q = (s >> 8) * IMW + (s & 255);
        int p = r * IMW + c;
        float v0 = img[3 * q + 0];
        float v1 = img[3 * q + 1];
        float v2 = img[3 * q + 2];
        out[3 * p + 0] = fminf(fmaxf(v0, 0.0f), 1.0f);
        out[3 * p + 1] = fminf(fmaxf(v1, 0.0f), 1.0f);
        out[3 * p + 2] = fminf(fmaxf(v2, 0.0f), 1.0f);
    }
}

extern "C" void kernel_launch(void* const* d_in, const int* in_sizes, int n_in,
                              void* d_out, int out_size, void* d_ws, size_t ws_size,
                              hipStream_t stream) {
    const float* img = (const float*)d_in[0];
    const int2* dxy = (const int2*)d_in[1];
    float* out = (float*)d_out;
    hipLaunchKernelGGL(glass_onepass, dim3(IMH), dim3(256), 0, stream, img, dxy, out);
}